// Round 1
// baseline (159.655 us; speedup 1.0000x reference)
//
#include <hip/hip_runtime.h>
#include <hip/hip_bf16.h>

#define BATCH 16
#define LQ    2048
#define LKV   2048
#define DH    64
#define QT    64      // q rows per block
#define KT    64      // kv rows per tile
#define WAVES 4

typedef __attribute__((ext_vector_type(4))) float  f32x4;
typedef __attribute__((ext_vector_type(8))) __bf16 bf16x8;

// LDS strides (in elements). Chosen so b128 fragment reads are conflict-free:
// byte row-stride 272 (f32, 17*16) and 144 (bf16, 9*16) -> chunk%8 distinct
// within each 8-lane group.
#define QS 68    // f32 stride for Q staging tile
#define KS 72    // bf16 stride for K / V^T / P tiles

#define OFF_Q 0
#define SZ_Q  (QT * QS * 4)          // 17408
#define OFF_K (OFF_Q + SZ_Q)
#define SZ_K  (KT * KS * 2)          // 9216
#define OFF_V (OFF_K + SZ_K)
#define SZ_V  (KT * KS * 2)          // 9216
#define OFF_P (OFF_V + SZ_V)
#define SZ_P  (WAVES * 16 * KS * 2)  // 9216
#define SMEM_BYTES (OFF_P + SZ_P)    // 45056 B

__global__ __launch_bounds__(256, 2)
void attn_kernel(const float* __restrict__ Qg, const float* __restrict__ Kg,
                 const float* __restrict__ Vg, const int* __restrict__ scale_p,
                 float* __restrict__ Og)
{
    __shared__ __align__(16) char smem[SMEM_BYTES];
    float*  sQ = (float*) (smem + OFF_Q);
    __bf16* sK = (__bf16*)(smem + OFF_K);
    __bf16* sV = (__bf16*)(smem + OFF_V);
    __bf16* sP = (__bf16*)(smem + OFF_P);

    const int tid  = threadIdx.x;
    const int lane = tid & 63;
    const int wave = tid >> 6;
    const int g    = lane >> 4;   // quad index within wave
    const int n    = lane & 15;

    // batch-aware mapping: blocks of batch b land on XCD b%8 -> ~2 batches of
    // K/V working set per XCD L2 (2 MB < 4 MiB).
    const int b  = blockIdx.x & 15;
    const int qt = blockIdx.x >> 4;
    const int q0 = qt * QT;

    // scale_factor arrives as a 1-element array; reference divides by it.
    float inv_scale;
    {
        int iv = scale_p[0];
        if (iv > (1 << 23)) { union { int i; float f; } u; u.i = iv; inv_scale = 1.0f / u.f; }
        else                 inv_scale = 1.0f / (float)iv;
    }

    const size_t bq = (size_t)b * LQ * DH;   // same stride for Q/K/V/O

    // ---- stage this block's Q tile (64x64 f32) into LDS ----
    {
        const int row  = tid >> 2;
        const int dseg = (tid & 3) * 16;
        const float* gq = Qg + bq + (size_t)(q0 + row) * DH + dseg;
        f32x4 a0 = *(const f32x4*)(gq + 0);
        f32x4 a1 = *(const f32x4*)(gq + 4);
        f32x4 a2 = *(const f32x4*)(gq + 8);
        f32x4 a3 = *(const f32x4*)(gq + 12);
        f32x4* dst = (f32x4*)(sQ + row * QS + dseg);
        dst[0] = a0; dst[1] = a1; dst[2] = a2; dst[3] = a3;
    }
    __syncthreads();

    // ---- build per-wave Q A-fragments with bf16 hi/lo split ----
    // A-layout (16x16x32): lane holds A[m=lane&15][k = 8*(lane>>4)+j], j=0..7
    bf16x8 qhi[2], qlo[2];
    {
        const float* qr = sQ + (wave * 16 + n) * QS;
        for (int h = 0; h < 2; ++h) {
            const float* src = qr + h * 32 + g * 8;
            f32x4 x = *(const f32x4*)(src);
            f32x4 y = *(const f32x4*)(src + 4);
            float f[8];
            *(f32x4*)&f[0] = x; *(f32x4*)&f[4] = y;
            bf16x8 h8, l8;
            for (int i = 0; i < 8; ++i) {
                __bf16 hb = (__bf16)f[i];
                float  lo = f[i] - (float)hb;
                h8[i] = hb;
                l8[i] = (__bf16)lo;
            }
            qhi[h] = h8; qlo[h] = l8;
        }
    }

    // online-softmax state; rows handled by this lane: q = wave*16 + 4*g + r
    float m_run[4], l_run[4];
    f32x4 o[4];
    const f32x4 zero4 = {0.0f, 0.0f, 0.0f, 0.0f};
    for (int r = 0; r < 4; ++r) { m_run[r] = -INFINITY; l_run[r] = 0.0f; }
    for (int h = 0; h < 4; ++h) o[h] = zero4;

    const int srow = tid >> 2;          // staging row (kv index)
    const int sseg = (tid & 3) * 16;    // staging d segment

    for (int kt = 0; kt < LKV / KT; ++kt) {
        __syncthreads();   // previous iteration's fragment reads done

        // ---- stage K tile: row-major bf16 [kv][d] ----
        {
            const float* gk = Kg + bq + (size_t)(kt * KT + srow) * DH + sseg;
            f32x4 a0 = *(const f32x4*)(gk + 0);
            f32x4 a1 = *(const f32x4*)(gk + 4);
            f32x4 a2 = *(const f32x4*)(gk + 8);
            f32x4 a3 = *(const f32x4*)(gk + 12);
            float f[16];
            *(f32x4*)&f[0]  = a0; *(f32x4*)&f[4]  = a1;
            *(f32x4*)&f[8]  = a2; *(f32x4*)&f[12] = a3;
            bf16x8 w0, w1;
            for (int i = 0; i < 8; ++i) { w0[i] = (__bf16)f[i]; w1[i] = (__bf16)f[i + 8]; }
            *(bf16x8*)(sK + srow * KS + sseg)     = w0;
            *(bf16x8*)(sK + srow * KS + sseg + 8) = w1;
        }
        // ---- stage V tile transposed: bf16 [d][kv] ----
        {
            const float* gv = Vg + bq + (size_t)(kt * KT + srow) * DH + sseg;
            f32x4 a0 = *(const f32x4*)(gv + 0);
            f32x4 a1 = *(const f32x4*)(gv + 4);
            f32x4 a2 = *(const f32x4*)(gv + 8);
            f32x4 a3 = *(const f32x4*)(gv + 12);
            float f[16];
            *(f32x4*)&f[0]  = a0; *(f32x4*)&f[4]  = a1;
            *(f32x4*)&f[8]  = a2; *(f32x4*)&f[12] = a3;
            for (int i = 0; i < 16; ++i)
                sV[(sseg + i) * KS + srow] = (__bf16)f[i];
        }
        __syncthreads();

        // ---- S = (Qhi + Qlo) * K^T  (16 q-rows x 64 kv-cols per wave) ----
        // B-layout: lane holds B[k = 8*(lane>>4)+j][n = lane&15];
        // B[k=d][n=kv] = K[kv][d] -> read K[16c+n][32h + 8g .. +7] contiguous.
        f32x4 s[4];
        for (int c = 0; c < 4; ++c) s[c] = zero4;
        for (int c = 0; c < 4; ++c) {
            for (int h = 0; h < 2; ++h) {
                bf16x8 kf = *(const bf16x8*)(sK + (c * 16 + n) * KS + h * 32 + g * 8);
                s[c] = __builtin_amdgcn_mfma_f32_16x16x32_bf16(qhi[h], kf, s[c], 0, 0, 0);
                s[c] = __builtin_amdgcn_mfma_f32_16x16x32_bf16(qlo[h], kf, s[c], 0, 0, 0);
            }
        }
        // C-layout: lane holds S[q = 4*g + r][kv = 16*c + n], r=0..3
        for (int c = 0; c < 4; ++c)
            for (int r = 0; r < 4; ++r)
                s[c][r] *= inv_scale;

        // ---- online softmax (per q row; row lives across the 16 lanes of group g) ----
        float tm[4];
        for (int r = 0; r < 4; ++r)
            tm[r] = fmaxf(fmaxf(s[0][r], s[1][r]), fmaxf(s[2][r], s[3][r]));
        for (int off = 1; off < 16; off <<= 1)
            for (int r = 0; r < 4; ++r)
                tm[r] = fmaxf(tm[r], __shfl_xor(tm[r], off, 64));

        float alpha[4];
        for (int r = 0; r < 4; ++r) {
            float mn = fmaxf(m_run[r], tm[r]);
            alpha[r] = __expf(m_run[r] - mn);   // exp(-inf)=0 on first tile
            m_run[r] = mn;
        }
        float rs[4] = {0.f, 0.f, 0.f, 0.f};
        for (int c = 0; c < 4; ++c)
            for (int r = 0; r < 4; ++r) {
                float p = __expf(s[c][r] - m_run[r]);
                s[c][r] = p;
                rs[r] += p;
            }
        for (int off = 1; off < 16; off <<= 1)
            for (int r = 0; r < 4; ++r)
                rs[r] += __shfl_xor(rs[r], off, 64);
        for (int r = 0; r < 4; ++r)
            l_run[r] = l_run[r] * alpha[r] + rs[r];
        for (int h = 0; h < 4; ++h)
            for (int r = 0; r < 4; ++r)
                o[h][r] *= alpha[r];

        // ---- P: C-layout -> A-layout via wave-private LDS round-trip (m120) ----
        __bf16* pw = sP + wave * 16 * KS;
        for (int c = 0; c < 4; ++c)
            for (int r = 0; r < 4; ++r)
                pw[(4 * g + r) * KS + c * 16 + n] = (__bf16)s[c][r];
        __asm__ volatile("s_waitcnt lgkmcnt(0)" ::: "memory");  // wave-local drain

        bf16x8 pa[2];
        for (int kc = 0; kc < 2; ++kc)
            pa[kc] = *(const bf16x8*)(pw + n * KS + kc * 32 + g * 8);

        // ---- O += P * V  (B[k=kv][n=d] = V^T[d][kv] read contiguous in kv) ----
        for (int h2 = 0; h2 < 4; ++h2) {
            for (int kc = 0; kc < 2; ++kc) {
                bf16x8 vf = *(const bf16x8*)(sV + (h2 * 16 + n) * KS + kc * 32 + g * 8);
                o[h2] = __builtin_amdgcn_mfma_f32_16x16x32_bf16(pa[kc], vf, o[h2], 0, 0, 0);
            }
        }
    }

    // ---- epilogue: O row r = o / l ----
    for (int r = 0; r < 4; ++r) {
        float rl = 1.0f / l_run[r];
        const size_t qrow = (size_t)(q0 + wave * 16 + 4 * g + r);
        float* dst = Og + bq + qrow * DH + n;
        for (int h = 0; h < 4; ++h)
            dst[h * 16] = o[h][r] * rl;
    }
}

extern "C" void kernel_launch(void* const* d_in, const int* in_sizes, int n_in,
                              void* d_out, int out_size, void* d_ws, size_t ws_size,
                              hipStream_t stream)
{
    const float* Qg = (const float*)d_in[0];
    const float* Kg = (const float*)d_in[1];
    const float* Vg = (const float*)d_in[2];
    const int*   sc = (const int*)d_in[3];
    // d_in[4] = dropout_p (== 0, identity) — unused
    float* Og = (float*)d_out;

    dim3 grid(BATCH * (LQ / QT));   // 512 blocks
    dim3 block(WAVES * 64);         // 256 threads
    attn_kernel<<<grid, block, 0, stream>>>(Qg, Kg, Vg, sc, Og);
}

// Round 2
// 130.455 us; speedup vs baseline: 1.2238x; 1.2238x over previous
//
#include <hip/hip_runtime.h>
#include <hip/hip_bf16.h>

#define BATCH 16
#define LQ    2048
#define LKV   2048
#define DH    64
#define QT    64      // q rows per block
#define KT    64      // kv rows per tile
#define WAVES 4
#define NT    (LKV / KT)
#define LOG2E 1.4426950408889634f

typedef __attribute__((ext_vector_type(4))) float  f32x4;
typedef __attribute__((ext_vector_type(8))) __bf16 bf16x8;
typedef __attribute__((ext_vector_type(4))) __bf16 bf16x4;

// All bf16 tile strides = 72 elements (144 B): rows 16B-aligned for b128,
// bank patterns verified balanced (b128 frag reads: exactly 8 words/bank).
#define QS 68    // f32 stride for Q staging (272 B rows, 16B aligned)
#define KS 72
#define VS 72
#define PS 72

#define OFF_K 0
#define SZ_K  (KT * KS * 2)           // 9216
#define OFF_V (OFF_K + SZ_K)
#define SZ_V  (DH * VS * 2)           // 9216 (V^T: rows=d)
#define OFF_P (OFF_V + SZ_V)
#define SZ_P  (WAVES * 16 * PS * 2)   // 9216
#define SMEM_MAIN (OFF_P + SZ_P)      // 27648
#define SZ_Q  (QT * QS * 4)           // 17408 (aliases the K/V/P region)
#define SMEM_BYTES (SMEM_MAIN > SZ_Q ? SMEM_MAIN : SZ_Q)

__global__ __launch_bounds__(256, 2)
void attn_kernel(const float* __restrict__ Qg, const float* __restrict__ Kg,
                 const float* __restrict__ Vg, const int* __restrict__ scale_p,
                 float* __restrict__ Og)
{
    __shared__ __align__(16) char smem[SMEM_BYTES];
    float*  sQ = (float*) (smem);          // aliases sK/sV — consumed before kt loop
    __bf16* sK = (__bf16*)(smem + OFF_K);
    __bf16* sV = (__bf16*)(smem + OFF_V);  // V^T: [d][kv]
    __bf16* sP = (__bf16*)(smem + OFF_P);  // per-wave P: [q][kv]

    const int tid  = threadIdx.x;
    const int lane = tid & 63;
    const int wave = tid >> 6;
    const int g    = lane >> 4;
    const int n    = lane & 15;

    const int b  = blockIdx.x & 15;   // batch-major: spreads batches over XCDs
    const int qt = blockIdx.x >> 4;
    const int q0 = qt * QT;

    float inv_scale;
    {
        int iv = scale_p[0];
        if (iv > (1 << 23)) { union { int i; float f; } u; u.i = iv; inv_scale = 1.0f / u.f; }
        else                 inv_scale = 1.0f / (float)iv;
    }
    const float sc = inv_scale * LOG2E;   // softmax in exp2 domain

    const size_t bq = (size_t)b * LQ * DH;

    // ---- stage Q tile (64x64 f32) ----
    {
        const int row  = tid >> 2;
        const int dseg = (tid & 3) * 16;
        const float* gq = Qg + bq + (size_t)(q0 + row) * DH + dseg;
        f32x4 a0 = *(const f32x4*)(gq + 0);
        f32x4 a1 = *(const f32x4*)(gq + 4);
        f32x4 a2 = *(const f32x4*)(gq + 8);
        f32x4 a3 = *(const f32x4*)(gq + 12);
        f32x4* dst = (f32x4*)(sQ + row * QS + dseg);
        dst[0] = a0; dst[1] = a1; dst[2] = a2; dst[3] = a3;
    }
    __syncthreads();

    // ---- Q fragments (hi/lo bf16 split), B-operand layout for S^T = K·Q^T:
    // lane holds B[k = 8g+j][nq = n] = Q[q = w*16+n][d = 32h + 8g + j]
    bf16x8 qhi[2], qlo[2];
    {
        const float* qr = sQ + (wave * 16 + n) * QS;
        for (int h = 0; h < 2; ++h) {
            const float* src = qr + h * 32 + g * 8;
            f32x4 x = *(const f32x4*)(src);
            f32x4 y = *(const f32x4*)(src + 4);
            float f[8];
            *(f32x4*)&f[0] = x; *(f32x4*)&f[4] = y;
            bf16x8 h8, l8;
            for (int i = 0; i < 8; ++i) {
                __bf16 hb = (__bf16)f[i];
                h8[i] = hb;
                l8[i] = (__bf16)(f[i] - (float)hb);
            }
            qhi[h] = h8; qlo[h] = l8;
        }
    }

    // this lane's q row: q0 + wave*16 + n. Online state is scalar per lane.
    float m_run = -INFINITY, l_run = 0.0f;
    f32x4 o[4];   // O^T C-layout: o[mc][r] = O^T[d=16mc+4g+r][q]
    const f32x4 zero4 = {0.f, 0.f, 0.f, 0.f};
    for (int mc = 0; mc < 4; ++mc) o[mc] = zero4;

    // staging maps
    const int krow = tid >> 2, kseg = (tid & 3) * 16;      // K: one row, 16 d
    const int vd0  = (tid & 15) * 4, vkv0 = (tid >> 4) * 4; // V: 4x4 sub-tile
    const float* gK = Kg + bq + (size_t)krow * DH + kseg;
    const float* gV = Vg + bq + (size_t)vkv0 * DH + vd0;

    f32x4 kreg[4], vreg[4];
    for (int j = 0; j < 4; ++j) kreg[j] = *(const f32x4*)(gK + j * 4);
    for (int j = 0; j < 4; ++j) vreg[j] = *(const f32x4*)(gV + (size_t)j * DH);

    for (int kt = 0; kt < NT; ++kt) {
        __syncthreads();   // prior iteration's fragment reads complete

        // ---- write staged K (row-major) ----
        {
            float f[16];
            *(f32x4*)&f[0]  = kreg[0]; *(f32x4*)&f[4]  = kreg[1];
            *(f32x4*)&f[8]  = kreg[2]; *(f32x4*)&f[12] = kreg[3];
            bf16x8 w0, w1;
            for (int i = 0; i < 8; ++i) { w0[i] = (__bf16)f[i]; w1[i] = (__bf16)f[i + 8]; }
            *(bf16x8*)(sK + krow * KS + kseg)     = w0;
            *(bf16x8*)(sK + krow * KS + kseg + 8) = w1;
        }
        // ---- write staged V transposed (register 4x4 transpose, b64 stores) ----
        for (int i = 0; i < 4; ++i) {
            bf16x4 w;
            w[0] = (__bf16)vreg[0][i]; w[1] = (__bf16)vreg[1][i];
            w[2] = (__bf16)vreg[2][i]; w[3] = (__bf16)vreg[3][i];
            *(bf16x4*)(sV + (vd0 + i) * VS + vkv0) = w;
        }
        __syncthreads();

        // ---- prefetch next tile into registers (latency hides behind compute) ----
        if (kt + 1 < NT) {
            const float* gK2 = gK + (size_t)(kt + 1) * KT * DH;
            const float* gV2 = gV + (size_t)(kt + 1) * KT * DH;
            for (int j = 0; j < 4; ++j) kreg[j] = *(const f32x4*)(gK2 + j * 4);
            for (int j = 0; j < 4; ++j) vreg[j] = *(const f32x4*)(gV2 + (size_t)j * DH);
        }

        // ---- S^T = K·Q^T: A-frag from K row-major, B = Q registers ----
        // C-layout: lane holds S^T[kv = 16c + 4g + r][q = w*16 + n]
        f32x4 s[4];
        for (int c = 0; c < 4; ++c) s[c] = zero4;
        for (int c = 0; c < 4; ++c) {
            for (int h = 0; h < 2; ++h) {
                bf16x8 kf = *(const bf16x8*)(sK + (c * 16 + n) * KS + h * 32 + g * 8);
                s[c] = __builtin_amdgcn_mfma_f32_16x16x32_bf16(kf, qhi[h], s[c], 0, 0, 0);
                s[c] = __builtin_amdgcn_mfma_f32_16x16x32_bf16(kf, qlo[h], s[c], 0, 0, 0);
            }
        }
        for (int c = 0; c < 4; ++c)
            for (int r = 0; r < 4; ++r)
                s[c][r] *= sc;

        // ---- online softmax: one q row per lane, 16 kv in-register + 2 shuffles ----
        float tm = s[0][0];
        for (int c = 0; c < 4; ++c)
            for (int r = 0; r < 4; ++r)
                tm = fmaxf(tm, s[c][r]);
        tm = fmaxf(tm, __shfl_xor(tm, 16, 64));
        tm = fmaxf(tm, __shfl_xor(tm, 32, 64));

        float m_new = fmaxf(m_run, tm);
        float alpha = exp2f(m_run - m_new);
        float rs = 0.0f;
        for (int c = 0; c < 4; ++c)
            for (int r = 0; r < 4; ++r) {
                float p = exp2f(s[c][r] - m_new);
                s[c][r] = p;
                rs += p;
            }
        rs += __shfl_xor(rs, 16, 64);
        rs += __shfl_xor(rs, 32, 64);
        l_run = l_run * alpha + rs;
        m_run = m_new;
        for (int mc = 0; mc < 4; ++mc) o[mc] *= alpha;

        // ---- P^T (C-layout) -> P[q][kv] row-major in LDS, vectorized b64 ----
        __bf16* pw = sP + wave * 16 * PS;
        for (int c = 0; c < 4; ++c) {
            bf16x4 w;
            w[0] = (__bf16)s[c][0]; w[1] = (__bf16)s[c][1];
            w[2] = (__bf16)s[c][2]; w[3] = (__bf16)s[c][3];
            *(bf16x4*)(pw + n * PS + c * 16 + 4 * g) = w;
        }
        __asm__ volatile("s_waitcnt lgkmcnt(0)" ::: "memory");  // wave-private drain

        bf16x8 pb0 = *(const bf16x8*)(pw + n * PS + 0  + 8 * g);
        bf16x8 pb1 = *(const bf16x8*)(pw + n * PS + 32 + 8 * g);

        // ---- O^T += V^T · P^T: A-frag from V^T rows (contiguous b128) ----
        for (int mc = 0; mc < 4; ++mc) {
            bf16x8 vf0 = *(const bf16x8*)(sV + (mc * 16 + n) * VS + 0  + 8 * g);
            bf16x8 vf1 = *(const bf16x8*)(sV + (mc * 16 + n) * VS + 32 + 8 * g);
            o[mc] = __builtin_amdgcn_mfma_f32_16x16x32_bf16(vf0, pb0, o[mc], 0, 0, 0);
            o[mc] = __builtin_amdgcn_mfma_f32_16x16x32_bf16(vf1, pb1, o[mc], 0, 0, 0);
        }
    }

    // ---- epilogue: lane owns one q row; O^T[d][q] -> Og[q][d], f32x4 stores ----
    {
        float rl = 1.0f / l_run;
        const size_t qrow = (size_t)(q0 + wave * 16 + n);
        float* dst = Og + bq + qrow * DH;
        for (int mc = 0; mc < 4; ++mc) {
            f32x4 v = o[mc];
            v[0] *= rl; v[1] *= rl; v[2] *= rl; v[3] *= rl;
            *(f32x4*)(dst + mc * 16 + 4 * g) = v;
        }
    }
}

extern "C" void kernel_launch(void* const* d_in, const int* in_sizes, int n_in,
                              void* d_out, int out_size, void* d_ws, size_t ws_size,
                              hipStream_t stream)
{
    const float* Qg = (const float*)d_in[0];
    const float* Kg = (const float*)d_in[1];
    const float* Vg = (const float*)d_in[2];
    const int*   sc = (const int*)d_in[3];
    float* Og = (float*)d_out;

    dim3 grid(BATCH * (LQ / QT));   // 512 blocks
    dim3 block(WAVES * 64);         // 256 threads
    attn_kernel<<<grid, block, 0, stream>>>(Qg, Kg, Vg, sc, Og);
}

// Round 3
// 112.802 us; speedup vs baseline: 1.4154x; 1.1565x over previous
//
#include <hip/hip_runtime.h>
#include <hip/hip_bf16.h>
#include <cstdint>

#define BATCH 16
#define LQ    2048
#define LKV   2048
#define DH    64
#define QT    64
#define KT    64
#define WAVES 4
#define LOG2E 1.4426950408889634f

typedef __attribute__((ext_vector_type(4))) float  f32x4;
typedef __attribute__((ext_vector_type(8))) __bf16 bf16x8;
typedef __attribute__((ext_vector_type(4))) __bf16 bf16x4;

// ---------------- main kernel LDS layout (bytes) ----------------
// K tile [64 kv][64 d] bf16, rows 128 B, 16B-chunk XOR swizzle (seg ^= row&7)
// V^T tile [64 d][64 kv] bf16, same swizzle
// P per-wave [16 q][KT kv] bf16, stride 72 elems (conflict-free, hand-checked)
#define OFF_K 0
#define OFF_V 8192
#define PS    72
#define OFF_P 16384
#define SMEM_MAIN (OFF_P + WAVES * 16 * PS * 2)   // 25600 B

// async global->LDS DMA, 16 B/lane, LDS dst = wave-uniform base + lane*16
#define GLL16(gp, lp) __builtin_amdgcn_global_load_lds( \
    (const __attribute__((address_space(1))) uint32_t*)(gp), \
    (__attribute__((address_space(3))) uint32_t*)(lp), 16, 0, 0)

__device__ __forceinline__ float read_scale(const int* scale_p) {
    int iv = scale_p[0];
    if (iv > (1 << 23)) { union { int i; float f; } u; u.i = iv; return u.f; }
    return (float)iv;
}

// ---------------- prepass: K -> bf16 row-major, V -> bf16 transposed ----------------
__global__ __launch_bounds__(256) void preconv(
    const float* __restrict__ Kg, const float* __restrict__ Vg,
    __bf16* __restrict__ Kb, __bf16* __restrict__ Vt)
{
    __shared__ __bf16 sT[64 * 72];
    const int tid = threadIdx.x;
    const int b = blockIdx.x & 15;
    const int t = blockIdx.x >> 4;                 // kv tile of 64
    const size_t base = ((size_t)b * LKV + (size_t)t * 64) * DH;

    // K convert: thread -> row r, cols cs..cs+15 (coalesced in+out)
    {
        const int r = tid >> 2, cs = (tid & 3) * 16;
        const float* gk = Kg + base + (size_t)r * DH + cs;
        f32x4 a0 = *(const f32x4*)(gk + 0);
        f32x4 a1 = *(const f32x4*)(gk + 4);
        f32x4 a2 = *(const f32x4*)(gk + 8);
        f32x4 a3 = *(const f32x4*)(gk + 12);
        float f[16];
        *(f32x4*)&f[0] = a0; *(f32x4*)&f[4] = a1;
        *(f32x4*)&f[8] = a2; *(f32x4*)&f[12] = a3;
        bf16x8 w0, w1;
        for (int i = 0; i < 8; ++i) { w0[i] = (__bf16)f[i]; w1[i] = (__bf16)f[i + 8]; }
        __bf16* dst = Kb + base + (size_t)r * DH + cs;
        *(bf16x8*)dst = w0; *(bf16x8*)(dst + 8) = w1;
    }
    // V transpose: 4x4 register subtile -> LDS^T (pad 72) -> coalesced rows out
    {
        const int vd0 = (tid & 15) * 4, vk0 = (tid >> 4) * 4;
        const float* gv = Vg + base + (size_t)vk0 * DH + vd0;
        f32x4 vr[4];
        for (int j = 0; j < 4; ++j) vr[j] = *(const f32x4*)(gv + (size_t)j * DH);
        for (int i = 0; i < 4; ++i) {
            bf16x4 w;
            w[0] = (__bf16)vr[0][i]; w[1] = (__bf16)vr[1][i];
            w[2] = (__bf16)vr[2][i]; w[3] = (__bf16)vr[3][i];
            *(bf16x4*)(&sT[(vd0 + i) * 72 + vk0]) = w;
        }
    }
    __syncthreads();
    {
        const int d = tid >> 2, ks = (tid & 3) * 16;
        bf16x8 w0 = *(const bf16x8*)(&sT[d * 72 + ks]);
        bf16x8 w1 = *(const bf16x8*)(&sT[d * 72 + ks + 8]);
        __bf16* dst = Vt + ((size_t)b * DH + d) * LKV + (size_t)t * 64 + ks;
        *(bf16x8*)dst = w0; *(bf16x8*)(dst + 8) = w1;
    }
}

// ---------------- main attention kernel ----------------
// S^T = K·Q^T (MFMA, Q hi/lo bf16 split), max-free exp2 softmax, O^T += V^T·P^T.
template<int SPLITS>
__global__ __launch_bounds__(256, 4) void attn_main(
    const float* __restrict__ Qg, const __bf16* __restrict__ Kb,
    const __bf16* __restrict__ Vt, const int* __restrict__ scale_p,
    float* __restrict__ Og, float* __restrict__ Lg)
{
    __shared__ __align__(16) char smem[SMEM_MAIN];
    char*   sK = smem + OFF_K;
    char*   sV = smem + OFF_V;
    __bf16* sP = (__bf16*)(smem + OFF_P);

    const int tid  = threadIdx.x;
    const int lane = tid & 63;
    const int wave = tid >> 6;
    const int g    = lane >> 4;
    const int n    = lane & 15;

    const int b     = blockIdx.x & 15;          // all blocks of batch b -> same XCD (L2 locality)
    const int t2    = blockIdx.x >> 4;
    const int split = (SPLITS == 1) ? 0 : (t2 % SPLITS);
    const int qt    = (SPLITS == 1) ? t2 : (t2 / SPLITS);
    const int q0    = qt * QT;
    const int NTS   = LKV / (KT * SPLITS);
    const int kvbase = split * (LKV / SPLITS);

    const float sc = (1.0f / read_scale(scale_p)) * LOG2E;   // exp2-domain scale

    // ---- Q fragments (hi/lo bf16 split) directly from global (one-time) ----
    // B-operand for S^T: lane holds B[k=8g+j][q=n] = Q[q0+w*16+n][32h+8g+j]
    bf16x8 qhi[2], qlo[2];
    {
        const float* qr = Qg + ((size_t)b * LQ + q0 + wave * 16 + n) * DH;
        for (int h = 0; h < 2; ++h) {
            const float* src = qr + h * 32 + g * 8;
            f32x4 x = *(const f32x4*)(src);
            f32x4 y = *(const f32x4*)(src + 4);
            float f[8];
            *(f32x4*)&f[0] = x; *(f32x4*)&f[4] = y;
            bf16x8 h8, l8;
            for (int i = 0; i < 8; ++i) {
                __bf16 hb = (__bf16)f[i];
                h8[i] = hb;
                l8[i] = (__bf16)(f[i] - (float)hb);
            }
            qhi[h] = h8; qlo[h] = l8;
        }
    }

    // ---- loop-invariant LDS addresses ----
    // frag read (both K and V^T): row*128 + ((seg) ^ (n&7))*16, seg = 4h+g
    const int fOA = n * 128 + (((0 + g) ^ (n & 7)) << 4);   // h/sel = 0
    const int fOB = n * 128 + (((4 + g) ^ (n & 7)) << 4);   // h/sel = 1
    char* pwW = (char*)sP + wave * (16 * PS * 2) + n * (PS * 2) + g * 8;   // P writes (+c*32)
    char* pwR = (char*)sP + wave * (16 * PS * 2) + n * (PS * 2) + g * 16;  // P reads  (+sel*64)

    // ---- staging DMA addresses (XOR-swizzled chunk pick, coalesced 1KB/instr) ----
    const int r8  = lane >> 3;                   // row within 8-row group
    const int sgi = (lane & 7) ^ r8;             // global 16B-seg this lane fetches
    const char* kg0 = (const char*)(Kb + ((size_t)b * LKV + kvbase + wave * 16 + r8) * DH) + sgi * 16;
    const char* kg1 = kg0 + 8 * DH * 2;          // +8 rows
    const char* vg0 = (const char*)(Vt + ((size_t)b * DH + wave * 16 + r8) * LKV + kvbase) + sgi * 16;
    const char* vg1 = vg0 + 8 * LKV * 2;         // +8 d-rows
    char* lK0 = sK + wave * 16 * 128; char* lK1 = lK0 + 1024;
    char* lV0 = sV + wave * 16 * 128; char* lV1 = lV0 + 1024;

    float lsum = 0.0f;
    f32x4 o[4];
    const f32x4 zero4 = {0.f, 0.f, 0.f, 0.f};
    for (int mc = 0; mc < 4; ++mc) o[mc] = zero4;

    for (int kt = 0; kt < NTS; ++kt) {
        __syncthreads();                         // prior frag reads done
        GLL16(kg0, lK0); GLL16(kg1, lK1);
        GLL16(vg0, lV0); GLL16(vg1, lV1);
        kg0 += KT * DH * 2; kg1 += KT * DH * 2;  // next kv tile
        vg0 += KT * 2;      vg1 += KT * 2;
        __syncthreads();                         // vmcnt(0) drain -> tile visible

        // ---- S^T = K·Q^T ----
        f32x4 s[4];
        for (int c = 0; c < 4; ++c) s[c] = zero4;
        for (int c = 0; c < 4; ++c) {
            bf16x8 kf0 = *(const bf16x8*)(sK + c * 2048 + fOA);
            bf16x8 kf1 = *(const bf16x8*)(sK + c * 2048 + fOB);
            s[c] = __builtin_amdgcn_mfma_f32_16x16x32_bf16(kf0, qhi[0], s[c], 0, 0, 0);
            s[c] = __builtin_amdgcn_mfma_f32_16x16x32_bf16(kf0, qlo[0], s[c], 0, 0, 0);
            s[c] = __builtin_amdgcn_mfma_f32_16x16x32_bf16(kf1, qhi[1], s[c], 0, 0, 0);
            s[c] = __builtin_amdgcn_mfma_f32_16x16x32_bf16(kf1, qlo[1], s[c], 0, 0, 0);
        }

        // ---- max-free softmax numerator: p = 2^(s*sc); accumulate l; pack P ----
        for (int c = 0; c < 4; ++c) {
            float p0 = __builtin_amdgcn_exp2f(s[c][0] * sc);
            float p1 = __builtin_amdgcn_exp2f(s[c][1] * sc);
            float p2 = __builtin_amdgcn_exp2f(s[c][2] * sc);
            float p3 = __builtin_amdgcn_exp2f(s[c][3] * sc);
            lsum += (p0 + p1) + (p2 + p3);
            bf16x4 w;
            w[0] = (__bf16)p0; w[1] = (__bf16)p1; w[2] = (__bf16)p2; w[3] = (__bf16)p3;
            *(bf16x4*)(pwW + c * 32) = w;        // P[q=n][kv=16c+4g+r]
        }
        __asm__ volatile("s_waitcnt lgkmcnt(0)" ::: "memory");  // wave-private P drain

        bf16x8 pb0 = *(const bf16x8*)(pwR);        // P^T B-frag, kv 0..31
        bf16x8 pb1 = *(const bf16x8*)(pwR + 64);   // kv 32..63

        // ---- O^T += V^T · P^T ----
        for (int mc = 0; mc < 4; ++mc) {
            bf16x8 vf0 = *(const bf16x8*)(sV + mc * 2048 + fOA);
            bf16x8 vf1 = *(const bf16x8*)(sV + mc * 2048 + fOB);
            o[mc] = __builtin_amdgcn_mfma_f32_16x16x32_bf16(vf0, pb0, o[mc], 0, 0, 0);
            o[mc] = __builtin_amdgcn_mfma_f32_16x16x32_bf16(vf1, pb1, o[mc], 0, 0, 0);
        }
    }

    // ---- one-time l reduction across the 4 g-lanes of each q row ----
    lsum += __shfl_xor(lsum, 16, 64);
    lsum += __shfl_xor(lsum, 32, 64);

    const size_t qrow = (size_t)(q0 + wave * 16 + n);
    if (SPLITS == 1) {
        float rl = 1.0f / lsum;
        float* dst = Og + ((size_t)b * LQ + qrow) * DH + 4 * g;
        for (int mc = 0; mc < 4; ++mc) {
            f32x4 v = o[mc];
            v[0] *= rl; v[1] *= rl; v[2] *= rl; v[3] *= rl;
            *(f32x4*)(dst + mc * 16) = v;
        }
    } else {
        float* dst = Og + (((size_t)split * BATCH + b) * LQ + qrow) * DH + 4 * g;
        for (int mc = 0; mc < 4; ++mc)
            *(f32x4*)(dst + mc * 16) = o[mc];
        if (g == 0)
            Lg[((size_t)split * BATCH + b) * LQ + qrow] = lsum;
    }
}

// ---------------- combine: out = (O0+O1)/(l0+l1) ----------------
__global__ __launch_bounds__(256) void combine2(
    const float* __restrict__ Op, const float* __restrict__ Lg,
    float* __restrict__ Og)
{
    const size_t gid = (size_t)blockIdx.x * 256 + threadIdx.x;  // 524288
    const size_t row = gid >> 4;                                // [0, 32768)
    const int    c4  = (int)(gid & 15) * 4;
    const size_t SO  = (size_t)BATCH * LQ * DH;
    f32x4 a  = *(const f32x4*)(Op + row * DH + c4);
    f32x4 b2 = *(const f32x4*)(Op + SO + row * DH + c4);
    float rl = 1.0f / (Lg[row] + Lg[(size_t)BATCH * LQ + row]);
    f32x4 v;
    for (int i = 0; i < 4; ++i) v[i] = (a[i] + b2[i]) * rl;
    *(f32x4*)(Og + row * DH + c4) = v;
}

// ---------------- fallback (round-2 kernel, proven): tiny-ws tier ----------------
#define FQS 68
#define FKS 72
#define F_OFF_K 0
#define F_SZ_K  (KT * FKS * 2)
#define F_OFF_V (F_OFF_K + F_SZ_K)
#define F_SZ_V  (DH * FKS * 2)
#define F_OFF_P (F_OFF_V + F_SZ_V)
#define F_SZ_P  (WAVES * 16 * FKS * 2)
#define F_SMEM_MAIN (F_OFF_P + F_SZ_P)
#define F_SZ_Q  (QT * FQS * 4)
#define F_SMEM (F_SMEM_MAIN > F_SZ_Q ? F_SMEM_MAIN : F_SZ_Q)

__global__ __launch_bounds__(256, 2)
void attn_fallback(const float* __restrict__ Qg, const float* __restrict__ Kg,
                   const float* __restrict__ Vg, const int* __restrict__ scale_p,
                   float* __restrict__ Og)
{
    __shared__ __align__(16) char smem[F_SMEM];
    float*  sQ = (float*) (smem);
    __bf16* sK = (__bf16*)(smem + F_OFF_K);
    __bf16* sV = (__bf16*)(smem + F_OFF_V);
    __bf16* sP = (__bf16*)(smem + F_OFF_P);

    const int tid  = threadIdx.x;
    const int lane = tid & 63;
    const int wave = tid >> 6;
    const int g    = lane >> 4;
    const int n    = lane & 15;
    const int b  = blockIdx.x & 15;
    const int qt = blockIdx.x >> 4;
    const int q0 = qt * QT;
    const float scv = (1.0f / read_scale(scale_p)) * LOG2E;
    const size_t bq = (size_t)b * LQ * DH;

    {
        const int row = tid >> 2, dseg = (tid & 3) * 16;
        const float* gq = Qg + bq + (size_t)(q0 + row) * DH + dseg;
        f32x4 a0 = *(const f32x4*)(gq + 0), a1 = *(const f32x4*)(gq + 4);
        f32x4 a2 = *(const f32x4*)(gq + 8), a3 = *(const f32x4*)(gq + 12);
        f32x4* dst = (f32x4*)(sQ + row * FQS + dseg);
        dst[0] = a0; dst[1] = a1; dst[2] = a2; dst[3] = a3;
    }
    __syncthreads();

    bf16x8 qhi[2], qlo[2];
    {
        const float* qr = sQ + (wave * 16 + n) * FQS;
        for (int h = 0; h < 2; ++h) {
            const float* src = qr + h * 32 + g * 8;
            f32x4 x = *(const f32x4*)(src), y = *(const f32x4*)(src + 4);
            float f[8];
            *(f32x4*)&f[0] = x; *(f32x4*)&f[4] = y;
            bf16x8 h8, l8;
            for (int i = 0; i < 8; ++i) {
                __bf16 hb = (__bf16)f[i];
                h8[i] = hb; l8[i] = (__bf16)(f[i] - (float)hb);
            }
            qhi[h] = h8; qlo[h] = l8;
        }
    }

    float lsum = 0.0f;
    f32x4 o[4];
    const f32x4 zero4 = {0.f, 0.f, 0.f, 0.f};
    for (int mc = 0; mc < 4; ++mc) o[mc] = zero4;

    const int krow = tid >> 2, kseg = (tid & 3) * 16;
    const int vd0 = (tid & 15) * 4, vkv0 = (tid >> 4) * 4;
    const float* gK = Kg + bq + (size_t)krow * DH + kseg;
    const float* gV = Vg + bq + (size_t)vkv0 * DH + vd0;
    f32x4 kreg[4], vreg[4];
    for (int j = 0; j < 4; ++j) kreg[j] = *(const f32x4*)(gK + j * 4);
    for (int j = 0; j < 4; ++j) vreg[j] = *(const f32x4*)(gV + (size_t)j * DH);

    for (int kt = 0; kt < LKV / KT; ++kt) {
        __syncthreads();
        {
            float f[16];
            *(f32x4*)&f[0] = kreg[0]; *(f32x4*)&f[4] = kreg[1];
            *(f32x4*)&f[8] = kreg[2]; *(f32x4*)&f[12] = kreg[3];
            bf16x8 w0, w1;
            for (int i = 0; i < 8; ++i) { w0[i] = (__bf16)f[i]; w1[i] = (__bf16)f[i + 8]; }
            *(bf16x8*)(sK + krow * FKS + kseg) = w0;
            *(bf16x8*)(sK + krow * FKS + kseg + 8) = w1;
        }
        for (int i = 0; i < 4; ++i) {
            bf16x4 w;
            w[0] = (__bf16)vreg[0][i]; w[1] = (__bf16)vreg[1][i];
            w[2] = (__bf16)vreg[2][i]; w[3] = (__bf16)vreg[3][i];
            *(bf16x4*)(sV + (vd0 + i) * FKS + vkv0) = w;
        }
        __syncthreads();
        if (kt + 1 < LKV / KT) {
            const float* gK2 = gK + (size_t)(kt + 1) * KT * DH;
            const float* gV2 = gV + (size_t)(kt + 1) * KT * DH;
            for (int j = 0; j < 4; ++j) kreg[j] = *(const f32x4*)(gK2 + j * 4);
            for (int j = 0; j < 4; ++j) vreg[j] = *(const f32x4*)(gV2 + (size_t)j * DH);
        }

        f32x4 s[4];
        for (int c = 0; c < 4; ++c) s[c] = zero4;
        for (int c = 0; c < 4; ++c) {
            for (int h = 0; h < 2; ++h) {
                bf16x8 kf = *(const bf16x8*)(sK + (c * 16 + n) * FKS + h * 32 + g * 8);
                s[c] = __builtin_amdgcn_mfma_f32_16x16x32_bf16(kf, qhi[h], s[c], 0, 0, 0);
                s[c] = __builtin_amdgcn_mfma_f32_16x16x32_bf16(kf, qlo[h], s[c], 0, 0, 0);
            }
        }
        __bf16* pw = sP + wave * 16 * FKS;
        for (int c = 0; c < 4; ++c) {
            float p0 = __builtin_amdgcn_exp2f(s[c][0] * scv);
            float p1 = __builtin_amdgcn_exp2f(s[c][1] * scv);
            float p2 = __builtin_amdgcn_exp2f(s[c][2] * scv);
            float p3 = __builtin_amdgcn_exp2f(s[c][3] * scv);
            lsum += (p0 + p1) + (p2 + p3);
            bf16x4 w;
            w[0] = (__bf16)p0; w[1] = (__bf16)p1; w[2] = (__bf16)p2; w[3] = (__bf16)p3;
            *(bf16x4*)(pw + n * FKS + c * 16 + 4 * g) = w;
        }
        __asm__ volatile("s_waitcnt lgkmcnt(0)" ::: "memory");
        bf16x8 pb0 = *(const bf16x8*)(pw + n * FKS + 0  + 8 * g);
        bf16x8 pb1 = *(const bf16x8*)(pw + n * FKS + 32 + 8 * g);
        for (int mc = 0; mc < 4; ++mc) {
            bf16x8 vf0 = *(const bf16x8*)(sV + (mc * 16 + n) * FKS + 0  + 8 * g);
            bf16x8 vf1 = *(const bf16x8*)(sV + (mc * 16 + n) * FKS + 32 + 8 * g);
            o[mc] = __builtin_amdgcn_mfma_f32_16x16x32_bf16(vf0, pb0, o[mc], 0, 0, 0);
            o[mc] = __builtin_amdgcn_mfma_f32_16x16x32_bf16(vf1, pb1, o[mc], 0, 0, 0);
        }
    }
    lsum += __shfl_xor(lsum, 16, 64);
    lsum += __shfl_xor(lsum, 32, 64);
    {
        float rl = 1.0f / lsum;
        float* dst = Og + bq + (size_t)(q0 + wave * 16 + n) * DH;
        for (int mc = 0; mc < 4; ++mc) {
            f32x4 v = o[mc];
            v[0] *= rl; v[1] *= rl; v[2] *= rl; v[3] *= rl;
            *(f32x4*)(dst + mc * 16 + 4 * g) = v;
        }
    }
}

// ---------------- launch ----------------
extern "C" void kernel_launch(void* const* d_in, const int* in_sizes, int n_in,
                              void* d_out, int out_size, void* d_ws, size_t ws_size,
                              hipStream_t stream)
{
    const float* Qg = (const float*)d_in[0];
    const float* Kg = (const float*)d_in[1];
    const float* Vg = (const float*)d_in[2];
    const int*   sc = (const int*)d_in[3];
    float* Og = (float*)d_out;

    const size_t szKb = (size_t)BATCH * LKV * DH * 2;        // 4 MB
    const size_t oV   = szKb;
    const size_t oO   = 2 * szKb;                            // 8.39 MB
    const size_t szOp = (size_t)2 * BATCH * LQ * DH * 4;     // 16.78 MB
    const size_t oL   = oO + szOp;
    const size_t need1 = oL + (size_t)2 * BATCH * LQ * 4;    // ~25.4 MB
    const size_t need2 = oO;                                 // ~8.4 MB

    if (ws_size >= need1) {
        __bf16* Kb = (__bf16*)d_ws;
        __bf16* Vt = (__bf16*)((char*)d_ws + oV);
        float*  Op = (float*)((char*)d_ws + oO);
        float*  Lg = (float*)((char*)d_ws + oL);
        preconv<<<dim3(BATCH * (LKV / 64)), dim3(256), 0, stream>>>(Kg, Vg, Kb, Vt);
        attn_main<2><<<dim3(BATCH * (LQ / QT) * 2), dim3(256), 0, stream>>>(Qg, Kb, Vt, sc, Op, Lg);
        combine2<<<dim3((BATCH * LQ * DH / 4) / 256), dim3(256), 0, stream>>>(Op, Lg, Og);
    } else if (ws_size >= need2) {
        __bf16* Kb = (__bf16*)d_ws;
        __bf16* Vt = (__bf16*)((char*)d_ws + oV);
        preconv<<<dim3(BATCH * (LKV / 64)), dim3(256), 0, stream>>>(Kg, Vg, Kb, Vt);
        attn_main<1><<<dim3(BATCH * (LQ / QT)), dim3(256), 0, stream>>>(Qg, Kb, Vt, sc, Og, nullptr);
    } else {
        attn_fallback<<<dim3(BATCH * (LQ / QT)), dim3(256), 0, stream>>>(Qg, Kg, Vg, sc, Og);
    }
}

// Round 4
// 111.854 us; speedup vs baseline: 1.4274x; 1.0085x over previous
//
#include <hip/hip_runtime.h>
#include <hip/hip_bf16.h>
#include <cstdint>

#define BATCH 16
#define LQ    2048
#define LKV   2048
#define DH    64
#define QT    128    // q rows per block (32 per wave)
#define KT    64     // kv rows per tile
#define WAVES 4
#define LOG2E 1.4426950408889634f

typedef __attribute__((ext_vector_type(4))) float  f32x4;
typedef __attribute__((ext_vector_type(8))) __bf16 bf16x8;
typedef __attribute__((ext_vector_type(4))) __bf16 bf16x4;

// ---------------- main kernel LDS layout (bytes) ----------------
// K: 2 buffers x [64 kv][64 d] bf16, 128 B rows, 16B-chunk XOR swizzle (chunk ^= row&7)
// V^T: 2 buffers x [64 d][64 kv] bf16, same swizzle
// P per-wave [32 q][64 kv] bf16, stride 72 elems
#define OFF_K 0
#define OFF_V 16384
#define PS    72
#define OFF_P 32768
#define SMEM_MAIN (OFF_P + WAVES * 32 * PS * 2)   // 51200 B -> 2 blocks/CU

// async global->LDS DMA, 16 B/lane, LDS dst = wave-uniform base + lane*16
#define GLL16(gp, lp) __builtin_amdgcn_global_load_lds( \
    (const __attribute__((address_space(1))) uint32_t*)(gp), \
    (__attribute__((address_space(3))) uint32_t*)(lp), 16, 0, 0)

__device__ __forceinline__ float read_scale(const int* scale_p) {
    int iv = scale_p[0];
    if (iv > (1 << 23)) { union { int i; float f; } u; u.i = iv; return u.f; }
    return (float)iv;
}

// ---------------- prepass: K -> bf16 row-major, V -> bf16 transposed ----------------
__global__ __launch_bounds__(256) void preconv(
    const float* __restrict__ Kg, const float* __restrict__ Vg,
    __bf16* __restrict__ Kb, __bf16* __restrict__ Vt)
{
    __shared__ __bf16 sT[64 * 72];
    const int tid = threadIdx.x;
    const int b = blockIdx.x & 15;
    const int t = blockIdx.x >> 4;
    const size_t base = ((size_t)b * LKV + (size_t)t * 64) * DH;

    {
        const int r = tid >> 2, cs = (tid & 3) * 16;
        const float* gk = Kg + base + (size_t)r * DH + cs;
        f32x4 a0 = *(const f32x4*)(gk + 0);
        f32x4 a1 = *(const f32x4*)(gk + 4);
        f32x4 a2 = *(const f32x4*)(gk + 8);
        f32x4 a3 = *(const f32x4*)(gk + 12);
        float f[16];
        *(f32x4*)&f[0] = a0; *(f32x4*)&f[4] = a1;
        *(f32x4*)&f[8] = a2; *(f32x4*)&f[12] = a3;
        bf16x8 w0, w1;
        for (int i = 0; i < 8; ++i) { w0[i] = (__bf16)f[i]; w1[i] = (__bf16)f[i + 8]; }
        __bf16* dst = Kb + base + (size_t)r * DH + cs;
        *(bf16x8*)dst = w0; *(bf16x8*)(dst + 8) = w1;
    }
    {
        const int vd0 = (tid & 15) * 4, vk0 = (tid >> 4) * 4;
        const float* gv = Vg + base + (size_t)vk0 * DH + vd0;
        f32x4 vr[4];
        for (int j = 0; j < 4; ++j) vr[j] = *(const f32x4*)(gv + (size_t)j * DH);
        for (int i = 0; i < 4; ++i) {
            bf16x4 w;
            w[0] = (__bf16)vr[0][i]; w[1] = (__bf16)vr[1][i];
            w[2] = (__bf16)vr[2][i]; w[3] = (__bf16)vr[3][i];
            *(bf16x4*)(&sT[(vd0 + i) * 72 + vk0]) = w;
        }
    }
    __syncthreads();
    {
        const int d = tid >> 2, ks = (tid & 3) * 16;
        bf16x8 w0 = *(const bf16x8*)(&sT[d * 72 + ks]);
        bf16x8 w1 = *(const bf16x8*)(&sT[d * 72 + ks + 8]);
        __bf16* dst = Vt + ((size_t)b * DH + d) * LKV + (size_t)t * 64 + ks;
        *(bf16x8*)dst = w0; *(bf16x8*)(dst + 8) = w1;
    }
}

// ---------------- main attention kernel ----------------
// Each wave computes 32 q rows (2 n-blocks) so the K/V fragment reads amortize 2x.
// Single barrier per kv-iter; K/V LDS double-buffered, DMA for tile kt+1 issued
// right after the barrier that publishes tile kt (drained by the NEXT barrier).
template<int SPLITS>
__global__ __launch_bounds__(256, 2) void attn_main(
    const float* __restrict__ Qg, const __bf16* __restrict__ Kb,
    const __bf16* __restrict__ Vt, const int* __restrict__ scale_p,
    float* __restrict__ Og, float* __restrict__ Lg)
{
    __shared__ __align__(16) char smem[SMEM_MAIN];

    const int tid  = threadIdx.x;
    const int lane = tid & 63;
    const int wave = tid >> 6;
    const int g    = lane >> 4;
    const int n    = lane & 15;

    const int b     = blockIdx.x & 15;   // batch in low bits -> spread across XCDs
    const int t2    = blockIdx.x >> 4;
    const int split = (SPLITS == 1) ? 0 : (t2 & (SPLITS - 1));
    const int qt    = (SPLITS == 1) ? t2 : (t2 / SPLITS);
    const int q0    = qt * QT;
    const int NTS   = LKV / (KT * SPLITS);
    const int kvbase = split * (LKV / SPLITS);

    const float sc = (1.0f / read_scale(scale_p)) * LOG2E;

    // ---- staging DMA setup (XOR-swizzled 16B chunk pick) ----
    const int r8  = lane >> 3;
    const int sgi = (lane & 7) ^ r8;
    const char* kg0 = (const char*)(Kb + ((size_t)b * LKV + kvbase + wave * 16 + r8) * DH) + sgi * 16;
    const char* kg1 = kg0 + 8 * DH * 2;
    const char* vg0 = (const char*)(Vt + ((size_t)b * DH + wave * 16 + r8) * LKV + kvbase) + sgi * 16;
    const char* vg1 = vg0 + 8 * LKV * 2;
    const int kStep = KT * DH * 2;   // next kv tile in Kb
    const int vStep = KT * 2;        // next kv tile in Vt (row-interior step)

    // prologue: DMA tile 0 into buffer 0
    {
        char* lK = smem + OFF_K + wave * 2048;
        char* lV = smem + OFF_V + wave * 2048;
        GLL16(kg0, lK); GLL16(kg1, lK + 1024);
        GLL16(vg0, lV); GLL16(vg1, lV + 1024);
        kg0 += kStep; kg1 += kStep; vg0 += vStep; vg1 += vStep;
    }

    // ---- Q fragments (hi/lo bf16 split) for 2 n-blocks, direct from global ----
    // B-operand: lane holds B[k=8g+j][q=n] = Q[q0+wave*32+nb*16+n][32h+8g+j]
    bf16x8 qh[2][2], ql[2][2];
    for (int nb = 0; nb < 2; ++nb) {
        const float* qr = Qg + ((size_t)b * LQ + q0 + wave * 32 + nb * 16 + n) * DH;
        for (int h = 0; h < 2; ++h) {
            const float* src = qr + h * 32 + g * 8;
            f32x4 x = *(const f32x4*)(src);
            f32x4 y = *(const f32x4*)(src + 4);
            float f[8];
            *(f32x4*)&f[0] = x; *(f32x4*)&f[4] = y;
            bf16x8 h8, l8;
            for (int i = 0; i < 8; ++i) {
                __bf16 hb = (__bf16)f[i];
                h8[i] = hb;
                l8[i] = (__bf16)(f[i] - (float)hb);
            }
            qh[nb][h] = h8; ql[nb][h] = l8;
        }
    }

    // ---- loop-invariant LDS addresses ----
    const int fOA = n * 128 + (((0 + g) ^ (n & 7)) << 4);   // chunk g
    const int fOB = n * 128 + (((4 + g) ^ (n & 7)) << 4);   // chunk 4+g
    // P row q = nb*16+n, 144 B rows
    char* pwBase = smem + OFF_P + wave * (32 * PS * 2);
    char* pwW0 = pwBase + n * (PS * 2) + g * 8;              // + nb*16*144 + c*32
    char* pwR0 = pwBase + n * (PS * 2) + g * 16;             // + nb*16*144 + sel*64

    float lsum[2] = {0.0f, 0.0f};
    f32x4 o[2][4];
    const f32x4 zero4 = {0.f, 0.f, 0.f, 0.f};
    for (int nb = 0; nb < 2; ++nb)
        for (int mc = 0; mc < 4; ++mc) o[nb][mc] = zero4;

    for (int kt = 0; kt < NTS; ++kt) {
        __syncthreads();   // publishes tile kt (implicit vmcnt(0) drains this wave's DMA)
        const int cur = kt & 1;
        char* sK = smem + OFF_K + cur * 8192;
        char* sV = smem + OFF_V + cur * 8192;

        // prefetch tile kt+1 into the other buffer; drained by NEXT barrier
        if (kt + 1 < NTS) {
            char* lK = smem + OFF_K + (cur ^ 1) * 8192 + wave * 2048;
            char* lV = smem + OFF_V + (cur ^ 1) * 8192 + wave * 2048;
            GLL16(kg0, lK); GLL16(kg1, lK + 1024);
            GLL16(vg0, lV); GLL16(vg1, lV + 1024);
            kg0 += kStep; kg1 += kStep; vg0 += vStep; vg1 += vStep;
        }

        // ---- S^T = K·Q^T for both n-blocks (K frags read once) ----
        f32x4 s[2][4];
        for (int nb = 0; nb < 2; ++nb)
            for (int c = 0; c < 4; ++c) s[nb][c] = zero4;
        #pragma unroll
        for (int c = 0; c < 4; ++c) {
            bf16x8 kf0 = *(const bf16x8*)(sK + c * 2048 + fOA);
            bf16x8 kf1 = *(const bf16x8*)(sK + c * 2048 + fOB);
            #pragma unroll
            for (int nb = 0; nb < 2; ++nb) {
                s[nb][c] = __builtin_amdgcn_mfma_f32_16x16x32_bf16(kf0, qh[nb][0], s[nb][c], 0, 0, 0);
                s[nb][c] = __builtin_amdgcn_mfma_f32_16x16x32_bf16(kf0, ql[nb][0], s[nb][c], 0, 0, 0);
                s[nb][c] = __builtin_amdgcn_mfma_f32_16x16x32_bf16(kf1, qh[nb][1], s[nb][c], 0, 0, 0);
                s[nb][c] = __builtin_amdgcn_mfma_f32_16x16x32_bf16(kf1, ql[nb][1], s[nb][c], 0, 0, 0);
            }
        }

        // ---- max-free softmax numerator; pack P to LDS ----
        #pragma unroll
        for (int nb = 0; nb < 2; ++nb) {
            char* pw = pwW0 + nb * (16 * PS * 2);
            #pragma unroll
            for (int c = 0; c < 4; ++c) {
                float p0 = __builtin_amdgcn_exp2f(s[nb][c][0] * sc);
                float p1 = __builtin_amdgcn_exp2f(s[nb][c][1] * sc);
                float p2 = __builtin_amdgcn_exp2f(s[nb][c][2] * sc);
                float p3 = __builtin_amdgcn_exp2f(s[nb][c][3] * sc);
                lsum[nb] += (p0 + p1) + (p2 + p3);
                bf16x4 w;
                w[0] = (__bf16)p0; w[1] = (__bf16)p1; w[2] = (__bf16)p2; w[3] = (__bf16)p3;
                *(bf16x4*)(pw + c * 32) = w;
            }
        }
        __asm__ volatile("s_waitcnt lgkmcnt(0)" ::: "memory");  // wave-private P drain

        bf16x8 pb[2][2];
        #pragma unroll
        for (int nb = 0; nb < 2; ++nb) {
            char* pr = pwR0 + nb * (16 * PS * 2);
            pb[nb][0] = *(const bf16x8*)(pr);
            pb[nb][1] = *(const bf16x8*)(pr + 64);
        }

        // ---- O^T += V^T · P^T (V frags read once, used by both n-blocks) ----
        #pragma unroll
        for (int mc = 0; mc < 4; ++mc) {
            bf16x8 vf0 = *(const bf16x8*)(sV + mc * 2048 + fOA);
            bf16x8 vf1 = *(const bf16x8*)(sV + mc * 2048 + fOB);
            #pragma unroll
            for (int nb = 0; nb < 2; ++nb) {
                o[nb][mc] = __builtin_amdgcn_mfma_f32_16x16x32_bf16(vf0, pb[nb][0], o[nb][mc], 0, 0, 0);
                o[nb][mc] = __builtin_amdgcn_mfma_f32_16x16x32_bf16(vf1, pb[nb][1], o[nb][mc], 0, 0, 0);
            }
        }
    }

    // ---- l reduction (once) + store ----
    #pragma unroll
    for (int nb = 0; nb < 2; ++nb) {
        lsum[nb] += __shfl_xor(lsum[nb], 16, 64);
        lsum[nb] += __shfl_xor(lsum[nb], 32, 64);
        const size_t qrow = (size_t)(q0 + wave * 32 + nb * 16 + n);
        if (SPLITS == 1) {
            float rl = 1.0f / lsum[nb];
            float* dst = Og + ((size_t)b * LQ + qrow) * DH + 4 * g;
            for (int mc = 0; mc < 4; ++mc) {
                f32x4 v = o[nb][mc];
                v[0] *= rl; v[1] *= rl; v[2] *= rl; v[3] *= rl;
                *(f32x4*)(dst + mc * 16) = v;
            }
        } else {
            float* dst = Og + (((size_t)split * BATCH + b) * LQ + qrow) * DH + 4 * g;
            for (int mc = 0; mc < 4; ++mc)
                *(f32x4*)(dst + mc * 16) = o[nb][mc];
            if (g == 0)
                Lg[((size_t)split * BATCH + b) * LQ + qrow] = lsum[nb];
        }
    }
}

// ---------------- combine: out = (O0+O1)/(l0+l1) ----------------
__global__ __launch_bounds__(256) void combine2(
    const float* __restrict__ Op, const float* __restrict__ Lg,
    float* __restrict__ Og)
{
    const size_t gid = (size_t)blockIdx.x * 256 + threadIdx.x;
    const size_t row = gid >> 4;
    const int    c4  = (int)(gid & 15) * 4;
    const size_t SO  = (size_t)BATCH * LQ * DH;
    f32x4 a  = *(const f32x4*)(Op + row * DH + c4);
    f32x4 b2 = *(const f32x4*)(Op + SO + row * DH + c4);
    float rl = 1.0f / (Lg[row] + Lg[(size_t)BATCH * LQ + row]);
    f32x4 v;
    for (int i = 0; i < 4; ++i) v[i] = (a[i] + b2[i]) * rl;
    *(f32x4*)(Og + row * DH + c4) = v;
}

// ---------------- fallback (round-2 kernel, proven): tiny-ws tier ----------------
#define FQS 68
#define FKS 72
#define F_OFF_K 0
#define F_SZ_K  (KT * FKS * 2)
#define F_OFF_V (F_OFF_K + F_SZ_K)
#define F_SZ_V  (DH * FKS * 2)
#define F_OFF_P (F_OFF_V + F_SZ_V)
#define F_SZ_P  (WAVES * 16 * FKS * 2)
#define F_SMEM_MAIN (F_OFF_P + F_SZ_P)
#define F_SZ_Q  (64 * FQS * 4)
#define F_SMEM (F_SMEM_MAIN > F_SZ_Q ? F_SMEM_MAIN : F_SZ_Q)

__global__ __launch_bounds__(256, 2)
void attn_fallback(const float* __restrict__ Qg, const float* __restrict__ Kg,
                   const float* __restrict__ Vg, const int* __restrict__ scale_p,
                   float* __restrict__ Og)
{
    __shared__ __align__(16) char smem[F_SMEM];
    float*  sQ = (float*) (smem);
    __bf16* sK = (__bf16*)(smem + F_OFF_K);
    __bf16* sV = (__bf16*)(smem + F_OFF_V);
    __bf16* sP = (__bf16*)(smem + F_OFF_P);

    const int tid  = threadIdx.x;
    const int lane = tid & 63;
    const int wave = tid >> 6;
    const int g    = lane >> 4;
    const int n    = lane & 15;
    const int b  = blockIdx.x & 15;
    const int qt = blockIdx.x >> 4;
    const int q0 = qt * 64;
    const float scv = (1.0f / read_scale(scale_p)) * LOG2E;
    const size_t bq = (size_t)b * LQ * DH;

    {
        const int row = tid >> 2, dseg = (tid & 3) * 16;
        const float* gq = Qg + bq + (size_t)(q0 + row) * DH + dseg;
        f32x4 a0 = *(const f32x4*)(gq + 0), a1 = *(const f32x4*)(gq + 4);
        f32x4 a2 = *(const f32x4*)(gq + 8), a3 = *(const f32x4*)(gq + 12);
        f32x4* dst = (f32x4*)(sQ + row * FQS + dseg);
        dst[0] = a0; dst[1] = a1; dst[2] = a2; dst[3] = a3;
    }
    __syncthreads();

    bf16x8 qhi[2], qlo[2];
    {
        const float* qr = sQ + (wave * 16 + n) * FQS;
        for (int h = 0; h < 2; ++h) {
            const float* src = qr + h * 32 + g * 8;
            f32x4 x = *(const f32x4*)(src), y = *(const f32x4*)(src + 4);
            float f[8];
            *(f32x4*)&f[0] = x; *(f32x4*)&f[4] = y;
            bf16x8 h8, l8;
            for (int i = 0; i < 8; ++i) {
                __bf16 hb = (__bf16)f[i];
                h8[i] = hb; l8[i] = (__bf16)(f[i] - (float)hb);
            }
            qhi[h] = h8; qlo[h] = l8;
        }
    }

    float lsum = 0.0f;
    f32x4 o[4];
    const f32x4 zero4 = {0.f, 0.f, 0.f, 0.f};
    for (int mc = 0; mc < 4; ++mc) o[mc] = zero4;

    const int krow = tid >> 2, kseg = (tid & 3) * 16;
    const int vd0 = (tid & 15) * 4, vkv0 = (tid >> 4) * 4;
    const float* gK = Kg + bq + (size_t)krow * DH + kseg;
    const float* gV = Vg + bq + (size_t)vkv0 * DH + vd0;
    f32x4 kreg[4], vreg[4];
    for (int j = 0; j < 4; ++j) kreg[j] = *(const f32x4*)(gK + j * 4);
    for (int j = 0; j < 4; ++j) vreg[j] = *(const f32x4*)(gV + (size_t)j * DH);

    for (int kt = 0; kt < LKV / KT; ++kt) {
        __syncthreads();
        {
            float f[16];
            *(f32x4*)&f[0] = kreg[0]; *(f32x4*)&f[4] = kreg[1];
            *(f32x4*)&f[8] = kreg[2]; *(f32x4*)&f[12] = kreg[3];
            bf16x8 w0, w1;
            for (int i = 0; i < 8; ++i) { w0[i] = (__bf16)f[i]; w1[i] = (__bf16)f[i + 8]; }
            *(bf16x8*)(sK + krow * FKS + kseg) = w0;
            *(bf16x8*)(sK + krow * FKS + kseg + 8) = w1;
        }
        for (int i = 0; i < 4; ++i) {
            bf16x4 w;
            w[0] = (__bf16)vreg[0][i]; w[1] = (__bf16)vreg[1][i];
            w[2] = (__bf16)vreg[2][i]; w[3] = (__bf16)vreg[3][i];
            *(bf16x4*)(sV + (vd0 + i) * FKS + vkv0) = w;
        }
        __syncthreads();
        if (kt + 1 < LKV / KT) {
            const float* gK2 = gK + (size_t)(kt + 1) * KT * DH;
            const float* gV2 = gV + (size_t)(kt + 1) * KT * DH;
            for (int j = 0; j < 4; ++j) kreg[j] = *(const f32x4*)(gK2 + j * 4);
            for (int j = 0; j < 4; ++j) vreg[j] = *(const f32x4*)(gV2 + (size_t)j * DH);
        }

        f32x4 s[4];
        for (int c = 0; c < 4; ++c) s[c] = zero4;
        for (int c = 0; c < 4; ++c) {
            for (int h = 0; h < 2; ++h) {
                bf16x8 kf = *(const bf16x8*)(sK + (c * 16 + n) * FKS + h * 32 + g * 8);
                s[c] = __builtin_amdgcn_mfma_f32_16x16x32_bf16(kf, qhi[h], s[c], 0, 0, 0);
                s[c] = __builtin_amdgcn_mfma_f32_16x16x32_bf16(kf, qlo[h], s[c], 0, 0, 0);
            }
        }
        __bf16* pw = sP + wave * 16 * FKS;
        for (int c = 0; c < 4; ++c) {
            float p0 = __builtin_amdgcn_exp2f(s[c][0] * scv);
            float p1 = __builtin_amdgcn_exp2f(s[c][1] * scv);
            float p2 = __builtin_amdgcn_exp2f(s[c][2] * scv);
            float p3 = __builtin_amdgcn_exp2f(s[c][3] * scv);
            lsum += (p0 + p1) + (p2 + p3);
            bf16x4 w;
            w[0] = (__bf16)p0; w[1] = (__bf16)p1; w[2] = (__bf16)p2; w[3] = (__bf16)p3;
            *(bf16x4*)(pw + n * FKS + c * 16 + 4 * g) = w;
        }
        __asm__ volatile("s_waitcnt lgkmcnt(0)" ::: "memory");
        bf16x8 pb0 = *(const bf16x8*)(pw + n * FKS + 0  + 8 * g);
        bf16x8 pb1 = *(const bf16x8*)(pw + n * FKS + 32 + 8 * g);
        for (int mc = 0; mc < 4; ++mc) {
            bf16x8 vf0 = *(const bf16x8*)(sV + (mc * 16 + n) * FKS + 0  + 8 * g);
            bf16x8 vf1 = *(const bf16x8*)(sV + (mc * 16 + n) * FKS + 32 + 8 * g);
            o[mc] = __builtin_amdgcn_mfma_f32_16x16x32_bf16(vf0, pb0, o[mc], 0, 0, 0);
            o[mc] = __builtin_amdgcn_mfma_f32_16x16x32_bf16(vf1, pb1, o[mc], 0, 0, 0);
        }
    }
    lsum += __shfl_xor(lsum, 16, 64);
    lsum += __shfl_xor(lsum, 32, 64);
    {
        float rl = 1.0f / lsum;
        float* dst = Og + bq + (size_t)(q0 + wave * 16 + n) * DH;
        for (int mc = 0; mc < 4; ++mc) {
            f32x4 v = o[mc];
            v[0] *= rl; v[1] *= rl; v[2] *= rl; v[3] *= rl;
            *(f32x4*)(dst + mc * 16 + 4 * g) = v;
        }
    }
}

// ---------------- launch ----------------
extern "C" void kernel_launch(void* const* d_in, const int* in_sizes, int n_in,
                              void* d_out, int out_size, void* d_ws, size_t ws_size,
                              hipStream_t stream)
{
    const float* Qg = (const float*)d_in[0];
    const float* Kg = (const float*)d_in[1];
    const float* Vg = (const float*)d_in[2];
    const int*   sc = (const int*)d_in[3];
    float* Og = (float*)d_out;

    const size_t szKb = (size_t)BATCH * LKV * DH * 2;        // 4 MB
    const size_t oV   = szKb;
    const size_t oO   = 2 * szKb;                            // 8.39 MB
    const size_t szOp = (size_t)2 * BATCH * LQ * DH * 4;     // 16.78 MB
    const size_t oL   = oO + szOp;
    const size_t need1 = oL + (size_t)2 * BATCH * LQ * 4;    // ~25.4 MB
    const size_t need2 = oO;                                 // ~8.4 MB

    if (ws_size >= need1) {
        __bf16* Kb = (__bf16*)d_ws;
        __bf16* Vt = (__bf16*)((char*)d_ws + oV);
        float*  Op = (float*)((char*)d_ws + oO);
        float*  Lg = (float*)((char*)d_ws + oL);
        preconv<<<dim3(BATCH * (LKV / 64)), dim3(256), 0, stream>>>(Kg, Vg, Kb, Vt);
        attn_main<2><<<dim3(BATCH * (LQ / QT) * 2), dim3(256), 0, stream>>>(Qg, Kb, Vt, sc, Op, Lg);
        combine2<<<dim3((BATCH * LQ * DH / 4) / 256), dim3(256), 0, stream>>>(Op, Lg, Og);
    } else if (ws_size >= need2) {
        __bf16* Kb = (__bf16*)d_ws;
        __bf16* Vt = (__bf16*)((char*)d_ws + oV);
        preconv<<<dim3(BATCH * (LKV / 64)), dim3(256), 0, stream>>>(Kg, Vg, Kb, Vt);
        attn_main<1><<<dim3(BATCH * (LQ / QT)), dim3(256), 0, stream>>>(Qg, Kb, Vt, sc, Og, nullptr);
    } else {
        attn_fallback<<<dim3(BATCH * (LQ / 64)), dim3(256), 0, stream>>>(Qg, Kg, Vg, sc, Og);
    }
}